// Round 1
// baseline (355.803 us; speedup 1.0000x reference)
//
#include <hip/hip_runtime.h>
#include <math.h>

#define TPB 256
// Problem constants (verified against in_sizes at launch)
// N=50000, E=1600000, F_IN=4, F_OUT=32, T=12

__global__ void k_zero(int* __restrict__ p, int n) {
  int g = blockIdx.x * blockDim.x + threadIdx.x;
  if (g < n) p[g] = 0;
}

// Fold weights: AzT[f*4+k] = sum_j Wz[k][j]*Lz[j][f]; bzp[f] = sum_j bz[j]*Lz[j][f] + lz[f]
// (H0=0 => only top 32 rows of Lz/Lh matter; R-gate entirely dead)
__global__ void k_pre(const float* __restrict__ Wz, const float* __restrict__ Lz, const float* __restrict__ lz,
                      const float* __restrict__ Wh, const float* __restrict__ Lh, const float* __restrict__ lh,
                      const float* __restrict__ bz, const float* __restrict__ bh,
                      const float* __restrict__ att,
                      float* __restrict__ AzT, float* __restrict__ AhT,
                      float* __restrict__ bzp, float* __restrict__ bhp, float* __restrict__ probs) {
  int t = threadIdx.x;
  if (t < 128) {
    int f = t >> 2, k = t & 3;
    float s = 0.f, s2 = 0.f;
    for (int j = 0; j < 32; ++j) {
      s  = fmaf(Wz[k * 32 + j], Lz[j * 32 + f], s);
      s2 = fmaf(Wh[k * 32 + j], Lh[j * 32 + f], s2);
    }
    AzT[t] = s; AhT[t] = s2;
  }
  if (t >= 128 && t < 160) {
    int f = t - 128;
    float s = lz[f], s2 = lh[f];
    for (int j = 0; j < 32; ++j) {
      s  = fmaf(bz[j], Lz[j * 32 + f], s);
      s2 = fmaf(bh[j], Lh[j * 32 + f], s2);
    }
    bzp[f] = s; bhp[f] = s2;
  }
  if (t == 160) {
    float m = att[0];
    for (int i = 1; i < 12; ++i) m = fmaxf(m, att[i]);
    float e[12]; float s = 0.f;
    for (int i = 0; i < 12; ++i) { e[i] = __expf(att[i] - m); s += e[i]; }
    for (int i = 0; i < 12; ++i) probs[i] = e[i] / s;
  }
}

__global__ void k_hist(const int* __restrict__ col, int E, int* __restrict__ counts) {
  int g = blockIdx.x * blockDim.x + threadIdx.x;
  if (g < E) atomicAdd(&counts[col[g]], 1);
}

// 3-stage exclusive scan of counts -> offsets, plus dinv = rsqrt(deg+1)
__global__ void k_scan1(const int* __restrict__ counts, int n, int* __restrict__ bsums) {
  __shared__ int s[TPB];
  int g = blockIdx.x * TPB + threadIdx.x;
  s[threadIdx.x] = (g < n) ? counts[g] : 0;
  __syncthreads();
  for (int off = TPB / 2; off > 0; off >>= 1) {
    if (threadIdx.x < off) s[threadIdx.x] += s[threadIdx.x + off];
    __syncthreads();
  }
  if (threadIdx.x == 0) bsums[blockIdx.x] = s[0];
}

__global__ void k_scan2(int* __restrict__ bsums, int nb, int n, int* __restrict__ offsets) {
  // nb <= 1024 (nb = ceil(50000/256) = 196)
  __shared__ int s[1024];
  int t = threadIdx.x;
  int v = (t < nb) ? bsums[t] : 0;
  s[t] = v;
  __syncthreads();
  for (int off = 1; off < 1024; off <<= 1) {
    int add = (t >= off) ? s[t - off] : 0;
    __syncthreads();
    s[t] += add;
    __syncthreads();
  }
  if (t < nb) bsums[t] = s[t] - v;          // exclusive block base
  if (t == 1023) offsets[n] = s[1023];      // total = E
}

__global__ void k_scan3(const int* __restrict__ counts, int n, const int* __restrict__ bsums,
                        int* __restrict__ offsets, float* __restrict__ dinv) {
  __shared__ int s[TPB];
  int g = blockIdx.x * TPB + threadIdx.x;
  int t = threadIdx.x;
  int v = (g < n) ? counts[g] : 0;
  s[t] = v;
  __syncthreads();
  for (int off = 1; off < TPB; off <<= 1) {
    int add = (t >= off) ? s[t - off] : 0;
    __syncthreads();
    s[t] += add;
    __syncthreads();
  }
  if (g < n) {
    offsets[g] = bsums[blockIdx.x] + s[t] - v;  // exclusive prefix
    dinv[g] = rsqrtf((float)(v + 1));           // +1 self loop; always > 0
  }
}

// CSR scatter: store (dinv[row], row) packed so the gather has no dependent dinv load
__global__ void k_scatter(const int* __restrict__ row, const int* __restrict__ col, int E,
                          const int* __restrict__ offsets, int* __restrict__ cursor,
                          const float* __restrict__ dinv, int2* __restrict__ csr) {
  int g = blockIdx.x * blockDim.x + threadIdx.x;
  if (g < E) {
    int c = col[g];
    int pos = atomicAdd(&cursor[c], 1);
    int r = row[g];
    int2 v; v.x = __float_as_int(dinv[r]); v.y = r;
    csr[offsets[c] + pos] = v;
  }
}

// Y[i] = dinv[i] * ( sum_{e: col=i} dinv[row_e]*x[row_e] + dinv[i]*x[i] ), 48 feats/node
// thread = (node, float4 chunk c in [0,12)); 12 lanes of one node broadcast-share csr reads
__global__ void k_agg(const float4* __restrict__ x4, const int2* __restrict__ csr,
                      const int* __restrict__ offsets, const float* __restrict__ dinv,
                      float4* __restrict__ Y4, int n) {
  int g = blockIdx.x * blockDim.x + threadIdx.x;
  if (g >= n * 12) return;
  int node = g / 12;
  int c = g - node * 12;
  float di = dinv[node];
  float4 xs = x4[node * 12 + c];
  float4 acc;
  acc.x = di * xs.x; acc.y = di * xs.y; acc.z = di * xs.z; acc.w = di * xs.w;
  int e0 = offsets[node], e1 = offsets[node + 1];
  for (int e = e0; e < e1; ++e) {
    int2 v = csr[e];
    float w = __int_as_float(v.x);
    float4 xv = x4[v.y * 12 + c];
    acc.x = fmaf(w, xv.x, acc.x);
    acc.y = fmaf(w, xv.y, acc.y);
    acc.z = fmaf(w, xv.z, acc.z);
    acc.w = fmaf(w, xv.w, acc.w);
  }
  acc.x *= di; acc.y *= di; acc.z *= di; acc.w *= di;
  Y4[node * 12 + c] = acc;
}

// Fused gates + attention + output linear. 8 nodes/block, thread = (node, f<32).
__global__ __launch_bounds__(256) void k_dense(
    const float4* __restrict__ Y4,
    const float* __restrict__ AzT, const float* __restrict__ AhT,
    const float* __restrict__ bzp, const float* __restrict__ bhp,
    const float* __restrict__ probs,
    const float* __restrict__ Wo, const float* __restrict__ bo,
    float* __restrict__ out, int n) {
  __shared__ float4 sAz4[32], sAh4[32];
  __shared__ float sbzp[32], sbhp[32], sprobs[12], sbo[12];
  __shared__ float sWo[384];
  __shared__ float4 sY4[96];           // 8 nodes x 48 floats
  __shared__ float sH[8 * 33];         // +1 pad: kills same-bank conflict in reduction

  int t = threadIdx.x;
  int nb = blockIdx.x * 8;

  if (t < 32) {
    sAz4[t] = ((const float4*)AzT)[t];
    sAh4[t] = ((const float4*)AhT)[t];
    sbzp[t] = bzp[t];
    sbhp[t] = bhp[t];
  }
  if (t >= 32 && t < 44) { sprobs[t - 32] = probs[t - 32]; sbo[t - 32] = bo[t - 32]; }
  for (int i = t; i < 384; i += 256) sWo[i] = Wo[i];
  if (t < 96) {
    int gi = nb * 12 + t;
    if (gi < n * 12) sY4[t] = Y4[gi];
  }
  __syncthreads();

  int ln = t >> 5, f = t & 31;
  float4 az = sAz4[f], ah = sAh4[f];
  float bzf = sbzp[f], bhf = sbhp[f];
  const float* y = (const float*)sY4 + ln * 48;  // [k*12 + tt]
  float Hf = 0.f;
#pragma unroll
  for (int tt = 0; tt < 12; ++tt) {
    float y0 = y[tt], y1 = y[12 + tt], y2 = y[24 + tt], y3 = y[36 + tt];
    float za = fmaf(az.x, y0, fmaf(az.y, y1, fmaf(az.z, y2, fmaf(az.w, y3, bzf))));
    float ha = fmaf(ah.x, y0, fmaf(ah.y, y1, fmaf(ah.z, y2, fmaf(ah.w, y3, bhf))));
    float Zc = 1.f / (1.f + __expf(za));     // (1 - sigmoid(za)) = sigmoid(-za)
    float ax = fabsf(ha);
    float e2 = __expf(-2.f * ax);
    float th = (1.f - e2) / (1.f + e2);      // tanh(|ha|), stable
    th = copysignf(th, ha);
    Hf = fmaf(sprobs[tt] * Zc, th, Hf);
  }
  sH[ln * 33 + f] = fmaxf(Hf, 0.f);          // relu
  __syncthreads();

  if (t < 96) {
    int ln2 = t / 12, p = t - ln2 * 12;
    int node2 = nb + ln2;
    if (node2 < n) {
      float acc = sbo[p];
      const float* h = &sH[ln2 * 33];
      const float* wv = &sWo[p];
#pragma unroll
      for (int f2 = 0; f2 < 32; ++f2) acc = fmaf(h[f2], wv[f2 * 12], acc);
      out[node2 * 12 + p] = acc;
    }
  }
}

extern "C" void kernel_launch(void* const* d_in, const int* in_sizes, int n_in,
                              void* d_out, int out_size, void* d_ws, size_t ws_size,
                              hipStream_t stream) {
  const float* x   = (const float*)d_in[0];
  const int*   ei  = (const int*)d_in[1];
  const float* att = (const float*)d_in[2];
  const float* Wz  = (const float*)d_in[3];
  const float* bz  = (const float*)d_in[4];
  const float* Lz  = (const float*)d_in[5];
  const float* lz  = (const float*)d_in[6];
  // d_in[7..10] = Wr, br, Lr, lr: dead (H0 == 0 => R unused)
  const float* Wh  = (const float*)d_in[11];
  const float* bh  = (const float*)d_in[12];
  const float* Lh  = (const float*)d_in[13];
  const float* lh  = (const float*)d_in[14];
  const float* Wo  = (const float*)d_in[15];
  const float* bo  = (const float*)d_in[16];
  float* out = (float*)d_out;

  const int N = in_sizes[0] / (4 * 12);
  const int E = in_sizes[1] / 2;
  const int* row = ei;
  const int* col = ei + E;

  // workspace carve-up (256B aligned chunks)
  char* w = (char*)d_ws;
  size_t o = 0;
  auto alloc = [&](size_t bytes) -> char* {
    o = (o + 255) & ~(size_t)255;
    char* p = w + o; o += bytes; return p;
  };
  float* pAzT   = (float*)alloc(128 * 4);
  float* pAhT   = (float*)alloc(128 * 4);
  float* pbzp   = (float*)alloc(32 * 4);
  float* pbhp   = (float*)alloc(32 * 4);
  float* pprobs = (float*)alloc(12 * 4);
  int*   pcnt2  = (int*)alloc((size_t)2 * N * 4);   // counts | cursor (contiguous for one zero pass)
  int*   pcounts = pcnt2;
  int*   pcursor = pcnt2 + N;
  int*   poffs  = (int*)alloc((size_t)(N + 1) * 4);
  float* pdinv  = (float*)alloc((size_t)N * 4);
  int2*  pcsr   = (int2*)alloc((size_t)E * 8);
  float* pY     = (float*)alloc((size_t)N * 48 * 4);
  int nbN = (N + TPB - 1) / TPB;                    // 196 (<=1024 required by k_scan2)
  int* pbsums = (int*)alloc((size_t)nbN * 4);
  (void)ws_size; (void)n_in; (void)out_size;

  k_pre<<<1, 256, 0, stream>>>(Wz, Lz, lz, Wh, Lh, lh, bz, bh, att,
                               pAzT, pAhT, pbzp, pbhp, pprobs);
  k_zero<<<(2 * N + TPB - 1) / TPB, TPB, 0, stream>>>(pcnt2, 2 * N);
  k_hist<<<(E + TPB - 1) / TPB, TPB, 0, stream>>>(col, E, pcounts);
  k_scan1<<<nbN, TPB, 0, stream>>>(pcounts, N, pbsums);
  k_scan2<<<1, 1024, 0, stream>>>(pbsums, nbN, N, poffs);
  k_scan3<<<nbN, TPB, 0, stream>>>(pcounts, N, pbsums, poffs, pdinv);
  k_scatter<<<(E + TPB - 1) / TPB, TPB, 0, stream>>>(row, col, E, poffs, pcursor, pdinv, pcsr);
  k_agg<<<(N * 12 + TPB - 1) / TPB, TPB, 0, stream>>>((const float4*)x, pcsr, poffs, pdinv,
                                                      (float4*)pY, N);
  k_dense<<<(N + 7) / 8, 256, 0, stream>>>((const float4*)pY, pAzT, pAhT, pbzp, pbhp, pprobs,
                                           Wo, bo, out, N);
}